// Round 13
// baseline (263.696 us; speedup 1.0000x reference)
//
#include <hip/hip_runtime.h>
#include <hip/hip_bf16.h>
#include <stdint.h>

typedef unsigned short u16;
typedef unsigned int u32;
typedef short short8 __attribute__((ext_vector_type(8)));
typedef float f32x4 __attribute__((ext_vector_type(4)));
typedef u32 u32x4 __attribute__((ext_vector_type(4)));
typedef u32 u32x2 __attribute__((ext_vector_type(2)));

#define DEV static __device__ __forceinline__

constexpr int Bsz = 4, Lseq = 2048, Dm = 1024, Hn = 16, Dk = 64;
constexpr float LOG2E = 1.44269504088896340736f;
constexpr float QSCALE = 0.125f * LOG2E;  // folded into Q projection

DEV u16 f2bf(float x) {
    u32 u = __builtin_bit_cast(u32, x);
    return (u16)((u + 0x7fffu + ((u >> 16) & 1u)) >> 16);
}

// pack 2 fp32 -> 2 bf16 in a u32 via HW v_cvt_pk_bf16_f32 path
DEV u32 pk2(float a, float b) {
    __hip_bfloat162 h = __float22bfloat162_rn(float2{a, b});
    u32 r;
    __builtin_memcpy(&r, &h, 4);
    return r;
}

// load 8 consecutive fp32, RNE to bf16, pack as u32x4
DEV u32x4 ld8_cvt(const float* p) {
    f32x4 lo = *(const f32x4*)p;
    f32x4 hi = *(const f32x4*)(p + 4);
    u32x4 r;
    r[0] = pk2(lo[0], lo[1]);
    r[1] = pk2(lo[2], lo[3]);
    r[2] = pk2(hi[0], hi[1]);
    r[3] = pk2(hi[2], hi[3]);
    return r;
}

// async global->LDS, 16B per lane; lds dest = wave-uniform base + lane*16
DEV void glds16(const void* g, void* l) {
    __builtin_amdgcn_global_load_lds(
        (const __attribute__((address_space(1))) void*)g,
        (__attribute__((address_space(3))) void*)l, 16, 0, 0);
}

// ---------------------------------------------------------------------------
// fp32 -> bf16 conversion: 3 weight matrices in one dispatch.
// ---------------------------------------------------------------------------
__global__ __launch_bounds__(256) void cvt_w3(
    const float* __restrict__ a, const float* __restrict__ b,
    const float* __restrict__ c, u16* __restrict__ d, int n8)
{
    int i = blockIdx.x * 256 + threadIdx.x;
    if (i >= n8) return;
    const float* s = blockIdx.y == 0 ? a : (blockIdx.y == 1 ? b : c);
    ((u32x4*)(d + (size_t)blockIdx.y * (size_t)n8 * 8))[i] = ld8_cvt(s + (long)i * 8);
}

// ---------------------------------------------------------------------------
// Output projection (R12-proven): out[M,N] fp32 = Cx(bf16) @ Wo^T + bo.
// A-side: bf16 via glds w=16. B-side: fp32 reg-staged with in-flight cvt.
// ---------------------------------------------------------------------------
__global__ __launch_bounds__(256) void gemm_oproj(
    const u16* __restrict__ A, const float* __restrict__ W,
    const float* __restrict__ bias, float* __restrict__ Cout)
{
    __shared__ u16 At[2][128 * 32];
    __shared__ u16 Bt[2][128 * 32];

    const int tid = threadIdx.x;
    const int lane = tid & 63, wid = tid >> 6;
    const int wr = wid >> 1, wc = wid & 1;
    const int mbase = blockIdx.x * 128, nbase = blockIdx.y * 128;

    f32x4 acc[4][4];
#pragma unroll
    for (int i = 0; i < 4; i++)
#pragma unroll
        for (int j = 0; j < 4; j++) acc[i][j] = (f32x4)0.f;

    const int srow = lane >> 2;
    const int sseg = (lane & 3) * 8;
    auto stageA = [&](int kt, int buf) {
#pragma unroll
        for (int c = 0; c < 2; c++) {
            const int sec = wid * 2 + c;
            glds16(A + (long)(mbase + sec * 16 + srow) * Dm + (long)kt * 32 + sseg,
                   &At[buf][sec * 512]);
        }
    };

    u32x4 vb[2];
    auto loadB = [&](int kt) {
#pragma unroll
        for (int i = 0; i < 2; i++) {
            int idx = i * 256 + tid;
            int row = idx >> 2, seg = idx & 3;
            vb[i] = ld8_cvt(W + (long)(nbase + row) * Dm + (long)kt * 32 + seg * 8);
        }
    };
    auto writeB = [&](int buf) {
#pragma unroll
        for (int i = 0; i < 2; i++) {
            int idx = i * 256 + tid;
            *(u32x4*)&Bt[buf][idx * 8] = vb[i];
        }
    };

    stageA(0, 0);
    loadB(0);
    writeB(0);
    __syncthreads();

    for (int kt = 0; kt < 32; kt++) {
        const int cur = kt & 1;
        const bool more = (kt + 1 < 32);
        if (more) {
            stageA(kt + 1, cur ^ 1);
            loadB(kt + 1);
        }
        short8 af[4], bfr[4];
#pragma unroll
        for (int mf = 0; mf < 4; mf++)
            af[mf] = *(const short8*)&At[cur][(wr * 64 + mf * 16 + (lane & 15)) * 32 + (lane >> 4) * 8];
#pragma unroll
        for (int nf = 0; nf < 4; nf++)
            bfr[nf] = *(const short8*)&Bt[cur][(wc * 64 + nf * 16 + (lane & 15)) * 32 + (lane >> 4) * 8];
        __builtin_amdgcn_s_setprio(1);
#pragma unroll
        for (int mf = 0; mf < 4; mf++)
#pragma unroll
            for (int nf = 0; nf < 4; nf++)
                acc[mf][nf] = __builtin_amdgcn_mfma_f32_16x16x32_bf16(af[mf], bfr[nf], acc[mf][nf], 0, 0, 0);
        __builtin_amdgcn_s_setprio(0);
        if (more) writeB(cur ^ 1);
        __syncthreads();
    }

#pragma unroll
    for (int nf = 0; nf < 4; nf++) {
        const int n = nbase + wc * 64 + nf * 16 + (lane & 15);
        const float bv = bias[n];
#pragma unroll
        for (int mf = 0; mf < 4; mf++) {
            const int m0 = mbase + wr * 64 + mf * 16 + (lane >> 4) * 4;
#pragma unroll
            for (int r = 0; r < 4; r++) {
                const int m = m0 + r;
                Cout[(long)m * Dm + n] = acc[mf][nf][r] + bv;
            }
        }
    }
}

// ---------------------------------------------------------------------------
// Fused QKV GEMM (R9/R11-proven): one 1536-block dispatch, t = blockIdx.y>>3
// selects {X, W slab, bias, scale, output} (block-uniform).
// A fp32 reg-staged with in-flight cvt; B bf16 via glds w=16.
// ---------------------------------------------------------------------------
__global__ __launch_bounds__(256) void gemm_qkv(
    const float* __restrict__ Xq, const float* __restrict__ Xk,
    const float* __restrict__ Xv, const u16* __restrict__ Wb3,
    const float* __restrict__ bq, const float* __restrict__ bk,
    const float* __restrict__ bv, u16* __restrict__ Out3)
{
    __shared__ u16 At[2][128 * 32];
    __shared__ u16 Bt[2][128 * 32];

    const int tid = threadIdx.x;
    const int lane = tid & 63, wid = tid >> 6;
    const int wr = wid >> 1, wc = wid & 1;
    const int mbase = blockIdx.x * 128;
    const int t = blockIdx.y >> 3;              // 0:Q 1:K 2:V (block-uniform)
    const int nbase = (blockIdx.y & 7) * 128;
    const float* X = t == 0 ? Xq : (t == 1 ? Xk : Xv);
    const u16* Bw = Wb3 + (size_t)t * Dm * Dm;
    const float* bias = t == 0 ? bq : (t == 1 ? bk : bv);
    const float scale = t == 0 ? QSCALE : 1.0f;
    u16* Cout = Out3 + (size_t)t * ((size_t)Bsz * Lseq * Dm);

    f32x4 acc[4][4];
#pragma unroll
    for (int i = 0; i < 4; i++)
#pragma unroll
        for (int j = 0; j < 4; j++) acc[i][j] = (f32x4)0.f;

    const int srow = lane >> 2;
    const int sseg = (lane & 3) * 8;
    auto stageB = [&](int kt, int buf) {
#pragma unroll
        for (int c = 0; c < 2; c++) {
            const int sec = wid * 2 + c;
            glds16(Bw + (long)(nbase + sec * 16 + srow) * Dm + (long)kt * 32 + sseg,
                   &Bt[buf][sec * 512]);
        }
    };

    u32x4 va[2];
    auto loadA = [&](int kt) {
#pragma unroll
        for (int i = 0; i < 2; i++) {
            int idx = i * 256 + tid;
            int row = idx >> 2, seg = idx & 3;
            va[i] = ld8_cvt(X + (long)(mbase + row) * Dm + (long)kt * 32 + seg * 8);
        }
    };
    auto writeA = [&](int buf) {
#pragma unroll
        for (int i = 0; i < 2; i++) {
            int idx = i * 256 + tid;
            *(u32x4*)&At[buf][idx * 8] = va[i];
        }
    };

    stageB(0, 0);
    loadA(0);
    writeA(0);
    __syncthreads();

    for (int kt = 0; kt < 32; kt++) {
        const int cur = kt & 1;
        const bool more = (kt + 1 < 32);
        if (more) {
            stageB(kt + 1, cur ^ 1);
            loadA(kt + 1);
        }
        short8 af[4], bfr[4];
#pragma unroll
        for (int mf = 0; mf < 4; mf++)
            af[mf] = *(const short8*)&At[cur][(wr * 64 + mf * 16 + (lane & 15)) * 32 + (lane >> 4) * 8];
#pragma unroll
        for (int nf = 0; nf < 4; nf++)
            bfr[nf] = *(const short8*)&Bt[cur][(wc * 64 + nf * 16 + (lane & 15)) * 32 + (lane >> 4) * 8];
        __builtin_amdgcn_s_setprio(1);
#pragma unroll
        for (int mf = 0; mf < 4; mf++)
#pragma unroll
            for (int nf = 0; nf < 4; nf++)
                acc[mf][nf] = __builtin_amdgcn_mfma_f32_16x16x32_bf16(af[mf], bfr[nf], acc[mf][nf], 0, 0, 0);
        __builtin_amdgcn_s_setprio(0);
        if (more) writeA(cur ^ 1);
        __syncthreads();
    }

#pragma unroll
    for (int nf = 0; nf < 4; nf++) {
        const int n = nbase + wc * 64 + nf * 16 + (lane & 15);
        const float bv = bias[n];
#pragma unroll
        for (int mf = 0; mf < 4; mf++) {
            const int m0 = mbase + wr * 64 + mf * 16 + (lane >> 4) * 4;
#pragma unroll
            for (int r = 0; r < 4; r++) {
                const int m = m0 + r;
                const float v = (acc[mf][nf][r] + bv) * scale;
                int b = m >> 11, l = m & 2047, h = n >> 6, dk = n & 63;
                long addr = ((long)(b * Hn + h) * Lseq + l) * Dk + dk;
                Cout[addr] = f2bf(v);
            }
        }
    }
}

// ---------------------------------------------------------------------------
// Flash attention with PAIRWISE-BALANCED q-tile scheduling.
// Causal work per q-tile qt is ∝ 2qt+2 kv-tiles (range 2..32): with one
// block per q-tile, all blocks co-resident, wall time = qt=15 stragglers
// while other CUs idle (measured 19.5% occupancy). Fix: grid (B*H, 8);
// block processes qt = y THEN qt = 15-y sequentially -> per-block work
// = 34 kv-tiles, EXACTLY uniform; 512 blocks all finish together.
// Inner body identical to R7/R11-proven version (48KB full-P).
// ---------------------------------------------------------------------------
__global__ __launch_bounds__(256) void attn_fwd(
    const u16* __restrict__ Qb, const u16* __restrict__ Kb,
    const u16* __restrict__ Vb, u16* __restrict__ Ctx)
{
    __shared__ u16 Kt[2][64 * 64];
    __shared__ u16 Vt[2][64 * 64];
    __shared__ u16 Pq[4][32 * 64];

    const int tid = threadIdx.x, lane = tid & 63, w = tid >> 6;
    const int bh = blockIdx.x;
    const long base = (long)bh * Lseq * Dk;
    const int b = bh >> 4, h = bh & 15;

    const int krow_in_w = lane >> 3;
    const int kseg = lane & 7;
    const int skv = tid >> 3, sdb = (tid & 7) * 8;

    auto stage_k = [&](int kvbase, int buf) {
#pragma unroll
        for (int c = 0; c < 2; c++) {
            int kv = w * 16 + c * 8 + krow_in_w;
            int d0 = ((kseg ^ (kv & 7)) * 8);
            glds16(Kb + base + (long)(kvbase + kv) * Dk + d0,
                   &Kt[buf][(w * 16 + c * 8) * 64]);
        }
    };

    for (int half = 0; half < 2; half++) {
        const int qt = half == 0 ? (int)blockIdx.y
                                 : (2 * (int)gridDim.y - 1 - (int)blockIdx.y);
        const int qw = qt * 128 + w * 32;

        // Q fragments in registers (log2 domain)
        short8 qfr[2][2];
#pragma unroll
        for (int qf = 0; qf < 2; qf++)
#pragma unroll
            for (int ks = 0; ks < 2; ks++) {
                int q = qw + qf * 16 + (lane & 15);
                int d0 = ks * 32 + (lane >> 4) * 8;
                qfr[qf][ks] = *(const short8*)(Qb + base + (long)q * Dk + d0);
            }

        f32x4 accT[4][2];  // ctx^T: [dkf][qf]
#pragma unroll
        for (int i = 0; i < 4; i++)
#pragma unroll
            for (int j = 0; j < 2; j++) accT[i][j] = (f32x4)0.f;
        float m_run[2] = {-__builtin_inff(), -__builtin_inff()};
        float l_part[2] = {0.f, 0.f};

        u32x4 vr[2];
        stage_k(0, 0);
#pragma unroll
        for (int i = 0; i < 2; i++)
            vr[i] = *(const u32x4*)(Vb + base + (long)(i * 32 + skv) * Dk + sdb);
#pragma unroll
        for (int i = 0; i < 2; i++) {
            int kv = i * 32 + skv;
            const u16* pv = (const u16*)&vr[i];
#pragma unroll
            for (int j = 0; j < 8; j++) {
                int d = sdb + j;
                Vt[0][d * 64 + (kv ^ ((((d & 7) ^ (d >> 3)) & 7) << 3))] = pv[j];
            }
        }
        __syncthreads();

        const int nkv = qt * 2 + 2;
        const int myn = ((qw + 31) >> 6) + 1;  // tiles this wave computes

        for (int kvt = 0; kvt < nkv; kvt++) {
            const int cur = kvt & 1;
            const bool more = (kvt + 1 < nkv);
            const int kvbase = kvt * 64;

            if (more) {
                stage_k(kvbase + 64, cur ^ 1);
#pragma unroll
                for (int i = 0; i < 2; i++)
                    vr[i] = *(const u32x4*)(Vb + base + (long)(kvbase + 64 + i * 32 + skv) * Dk + sdb);
            }

            if (kvt < myn) {
                // ---- S^T = K @ Q^T
                f32x4 st[4][2];
#pragma unroll
                for (int i = 0; i < 4; i++)
#pragma unroll
                    for (int j = 0; j < 2; j++) st[i][j] = (f32x4)0.f;
                __builtin_amdgcn_s_setprio(1);
#pragma unroll
                for (int ks = 0; ks < 2; ks++) {
                    short8 kf[4];
#pragma unroll
                    for (int kvf = 0; kvf < 4; kvf++) {
                        int row = kvf * 16 + (lane & 15);
                        int d0 = ks * 32 + (lane >> 4) * 8;
                        kf[kvf] = *(const short8*)&Kt[cur][row * 64 + (d0 ^ ((row & 7) << 3))];
                    }
#pragma unroll
                    for (int kvf = 0; kvf < 4; kvf++)
#pragma unroll
                        for (int qf = 0; qf < 2; qf++)
                            st[kvf][qf] = __builtin_amdgcn_mfma_f32_16x16x32_bf16(kf[kvf], qfr[qf][ks], st[kvf][qf], 0, 0, 0);
                }
                __builtin_amdgcn_s_setprio(0);

                // ---- causal mask (diagonal tiles only)
                if ((kvbase + 63) > qw) {
#pragma unroll
                    for (int qf = 0; qf < 2; qf++) {
                        const int q = qw + qf * 16 + (lane & 15);
#pragma unroll
                        for (int kvf = 0; kvf < 4; kvf++)
#pragma unroll
                            for (int r = 0; r < 4; r++) {
                                int kv = kvbase + kvf * 16 + (lane >> 4) * 4 + r;
                                if (kv > q) st[kvf][qf][r] = -1e30f;
                            }
                    }
                }

                // ---- online softmax (base 2), defer-max, lane-partial l
#pragma unroll
                for (int qf = 0; qf < 2; qf++) {
                    float tmax = st[0][qf][0];
#pragma unroll
                    for (int kvf = 0; kvf < 4; kvf++)
#pragma unroll
                        for (int r = 0; r < 4; r++) tmax = fmaxf(tmax, st[kvf][qf][r]);
                    tmax = fmaxf(tmax, __shfl_xor(tmax, 16, 64));
                    tmax = fmaxf(tmax, __shfl_xor(tmax, 32, 64));
                    const bool norescale = __all((int)(tmax <= m_run[qf] + 8.f));
                    if (!norescale) {
                        const float mnew = fmaxf(m_run[qf], tmax);
                        const float sc = __builtin_exp2f(m_run[qf] - mnew);
                        m_run[qf] = mnew;
                        l_part[qf] *= sc;
#pragma unroll
                        for (int dkf = 0; dkf < 4; dkf++)
#pragma unroll
                            for (int r = 0; r < 4; r++) accT[dkf][qf][r] *= sc;
                    }
                    const float mq = m_run[qf];
                    float ts = 0.f;
#pragma unroll
                    for (int kvf = 0; kvf < 4; kvf++)
#pragma unroll
                        for (int r = 0; r < 4; r++) {
                            float p = __builtin_exp2f(st[kvf][qf][r] - mq);
                            st[kvf][qf][r] = p;
                            ts += p;
                        }
                    l_part[qf] += ts;
                    const int qrow = qf * 16 + (lane & 15);
#pragma unroll
                    for (int kvf = 0; kvf < 4; kvf++) {
                        u32x2 pk;
                        pk[0] = pk2(st[kvf][qf][0], st[kvf][qf][1]);
                        pk[1] = pk2(st[kvf][qf][2], st[kvf][qf][3]);
                        int kvi = (kvf * 16 + (lane >> 4) * 4) ^ ((lane & 7) << 3);
                        *(u32x2*)&Pq[w][qrow * 64 + kvi] = pk;
                    }
                }

                // ---- PV: ctx^T += V^T @ P^T
#pragma unroll
                for (int kf2 = 0; kf2 < 2; kf2++) {
                    short8 vfr[4];
#pragma unroll
                    for (int dkf = 0; dkf < 4; dkf++) {
                        int d = dkf * 16 + (lane & 15);
                        int kvi = (kf2 * 32 + (lane >> 4) * 8) ^ ((((d & 7) ^ (d >> 3)) & 7) << 3);
                        vfr[dkf] = *(const short8*)&Vt[cur][d * 64 + kvi];
                    }
                    short8 pfr[2];
#pragma unroll
                    for (int qf = 0; qf < 2; qf++) {
                        int qrow = qf * 16 + (lane & 15);
                        int kvi = (kf2 * 32 + (lane >> 4) * 8) ^ ((lane & 7) << 3);
                        pfr[qf] = *(const short8*)&Pq[w][qrow * 64 + kvi];
                    }
                    __builtin_amdgcn_s_setprio(1);
#pragma unroll
                    for (int dkf = 0; dkf < 4; dkf++)
#pragma unroll
                        for (int qf = 0; qf < 2; qf++)
                            accT[dkf][qf] = __builtin_amdgcn_mfma_f32_16x16x32_bf16(vfr[dkf], pfr[qf], accT[dkf][qf], 0, 0, 0);
                    __builtin_amdgcn_s_setprio(0);
                }
            }

            // write staged V regs into the other buffer
            if (more) {
#pragma unroll
                for (int i = 0; i < 2; i++) {
                    int kv = i * 32 + skv;
                    const u16* pv = (const u16*)&vr[i];
#pragma unroll
                    for (int j = 0; j < 8; j++) {
                        int d = sdb + j;
                        Vt[cur ^ 1][d * 64 + (kv ^ ((((d & 7) ^ (d >> 3)) & 7) << 3))] = pv[j];
                    }
                }
            }
            __syncthreads();  // drains glds (vmcnt) for buf^1
        }

        // ---- epilogue: reduce l, divide, write bf16 [B,L,D]
#pragma unroll
        for (int qf = 0; qf < 2; qf++) {
            float l = l_part[qf];
            l += __shfl_xor(l, 16, 64);
            l += __shfl_xor(l, 32, 64);
            const float inv = 1.f / l;
            const int q = qw + qf * 16 + (lane & 15);
#pragma unroll
            for (int dkf = 0; dkf < 4; dkf++) {
                const int dk0 = dkf * 16 + (lane >> 4) * 4;
                u32x2 o;
                o[0] = pk2(accT[dkf][qf][0] * inv, accT[dkf][qf][1] * inv);
                o[1] = pk2(accT[dkf][qf][2] * inv, accT[dkf][qf][3] * inv);
                long addr = ((long)b * Lseq + q) * Dm + h * Dk + dk0;
                *(u32x2*)(Ctx + addr) = o;
            }
        }
        // last kv-iteration ended with __syncthreads(), so next half's
        // prologue can safely overwrite Kt[0]/Vt[0].
    }
}

// ---------------------------------------------------------------------------
extern "C" void kernel_launch(void* const* d_in, const int* in_sizes, int n_in,
                              void* d_out, int out_size, void* d_ws, size_t ws_size,
                              hipStream_t stream)
{
    const float* query = (const float*)d_in[0];
    const float* key_  = (const float*)d_in[1];
    const float* value = (const float*)d_in[2];
    const float* Wq = (const float*)d_in[3];
    const float* bq = (const float*)d_in[4];
    const float* Wk = (const float*)d_in[5];
    const float* bk = (const float*)d_in[6];
    const float* Wv = (const float*)d_in[7];
    const float* bv = (const float*)d_in[8];
    const float* Wo = (const float*)d_in[9];
    const float* bo = (const float*)d_in[10];
    // d_in[11] = attn_mask (bool causal) — derived from indices instead.

    float* out = (float*)d_out;
    const size_t tens = (size_t)Bsz * Lseq * Dm;   // 8,388,608
    const size_t wTot = (size_t)Dm * Dm;           // 1,048,576
    // ws layout (4*tens*2B = 67.1 MB, proven available):
    u16* Qb = (u16*)d_ws;        // bf16 [B,H,L,DK] (Q pre-scaled)
    u16* Kb = Qb + tens;
    u16* Vb = Kb + tens;
    u16* Cx = Vb + tens;         // attn output [B,L,D]
    u16* Wqb = Cx;               // Wq/Wk/Wv bf16 live in Cx slot until attn

    dim3 blk(256), g(64, 8), gq(64, 24);
    const int n8w = (int)(wTot / 8);
    const int gw = (n8w + 255) / 256;

    cvt_w3<<<dim3(gw, 3), blk, 0, stream>>>(Wq, Wk, Wv, Wqb, n8w);
    gemm_qkv<<<gq, blk, 0, stream>>>(query, key_, value, Wqb, bq, bk, bv, Qb);
    attn_fwd<<<dim3(Bsz * Hn, 8), blk, 0, stream>>>(Qb, Kb, Vb, Cx);
    gemm_oproj<<<g, blk, 0, stream>>>(Cx, Wo, bo, out);
}

// Round 14
// 212.936 us; speedup vs baseline: 1.2384x; 1.2384x over previous
//
#include <hip/hip_runtime.h>
#include <hip/hip_bf16.h>
#include <stdint.h>

typedef unsigned short u16;
typedef unsigned int u32;
typedef short short8 __attribute__((ext_vector_type(8)));
typedef float f32x4 __attribute__((ext_vector_type(4)));
typedef u32 u32x4 __attribute__((ext_vector_type(4)));
typedef u32 u32x2 __attribute__((ext_vector_type(2)));

#define DEV static __device__ __forceinline__

constexpr int Bsz = 4, Lseq = 2048, Dm = 1024, Hn = 16, Dk = 64;
constexpr float LOG2E = 1.44269504088896340736f;
constexpr float QSCALE = 0.125f * LOG2E;  // folded into Q projection

DEV u16 f2bf(float x) {
    u32 u = __builtin_bit_cast(u32, x);
    return (u16)((u + 0x7fffu + ((u >> 16) & 1u)) >> 16);
}

// pack 2 fp32 -> 2 bf16 in a u32 via HW v_cvt_pk_bf16_f32 path
DEV u32 pk2(float a, float b) {
    __hip_bfloat162 h = __float22bfloat162_rn(float2{a, b});
    u32 r;
    __builtin_memcpy(&r, &h, 4);
    return r;
}

// load 8 consecutive fp32, RNE to bf16, pack as u32x4
DEV u32x4 ld8_cvt(const float* p) {
    f32x4 lo = *(const f32x4*)p;
    f32x4 hi = *(const f32x4*)(p + 4);
    u32x4 r;
    r[0] = pk2(lo[0], lo[1]);
    r[1] = pk2(lo[2], lo[3]);
    r[2] = pk2(hi[0], hi[1]);
    r[3] = pk2(hi[2], hi[3]);
    return r;
}

// async global->LDS, 16B per lane; lds dest = wave-uniform base + lane*16
DEV void glds16(const void* g, void* l) {
    __builtin_amdgcn_global_load_lds(
        (const __attribute__((address_space(1))) void*)g,
        (__attribute__((address_space(3))) void*)l, 16, 0, 0);
}

// ---------------------------------------------------------------------------
// fp32 -> bf16 conversion: 3 weight matrices in one dispatch.
// ---------------------------------------------------------------------------
__global__ __launch_bounds__(256) void cvt_w3(
    const float* __restrict__ a, const float* __restrict__ b,
    const float* __restrict__ c, u16* __restrict__ d, int n8)
{
    int i = blockIdx.x * 256 + threadIdx.x;
    if (i >= n8) return;
    const float* s = blockIdx.y == 0 ? a : (blockIdx.y == 1 ? b : c);
    ((u32x4*)(d + (size_t)blockIdx.y * (size_t)n8 * 8))[i] = ld8_cvt(s + (long)i * 8);
}

// ---------------------------------------------------------------------------
// Output projection (R12-proven): out[M,N] fp32 = Cx(bf16) @ Wo^T + bo.
// A-side: bf16 via glds w=16. B-side: fp32 reg-staged with in-flight cvt.
// ---------------------------------------------------------------------------
__global__ __launch_bounds__(256) void gemm_oproj(
    const u16* __restrict__ A, const float* __restrict__ W,
    const float* __restrict__ bias, float* __restrict__ Cout)
{
    __shared__ u16 At[2][128 * 32];
    __shared__ u16 Bt[2][128 * 32];

    const int tid = threadIdx.x;
    const int lane = tid & 63, wid = tid >> 6;
    const int wr = wid >> 1, wc = wid & 1;
    const int mbase = blockIdx.x * 128, nbase = blockIdx.y * 128;

    f32x4 acc[4][4];
#pragma unroll
    for (int i = 0; i < 4; i++)
#pragma unroll
        for (int j = 0; j < 4; j++) acc[i][j] = (f32x4)0.f;

    const int srow = lane >> 2;
    const int sseg = (lane & 3) * 8;
    auto stageA = [&](int kt, int buf) {
#pragma unroll
        for (int c = 0; c < 2; c++) {
            const int sec = wid * 2 + c;
            glds16(A + (long)(mbase + sec * 16 + srow) * Dm + (long)kt * 32 + sseg,
                   &At[buf][sec * 512]);
        }
    };

    u32x4 vb[2];
    auto loadB = [&](int kt) {
#pragma unroll
        for (int i = 0; i < 2; i++) {
            int idx = i * 256 + tid;
            int row = idx >> 2, seg = idx & 3;
            vb[i] = ld8_cvt(W + (long)(nbase + row) * Dm + (long)kt * 32 + seg * 8);
        }
    };
    auto writeB = [&](int buf) {
#pragma unroll
        for (int i = 0; i < 2; i++) {
            int idx = i * 256 + tid;
            *(u32x4*)&Bt[buf][idx * 8] = vb[i];
        }
    };

    stageA(0, 0);
    loadB(0);
    writeB(0);
    __syncthreads();

    for (int kt = 0; kt < 32; kt++) {
        const int cur = kt & 1;
        const bool more = (kt + 1 < 32);
        if (more) {
            stageA(kt + 1, cur ^ 1);
            loadB(kt + 1);
        }
        short8 af[4], bfr[4];
#pragma unroll
        for (int mf = 0; mf < 4; mf++)
            af[mf] = *(const short8*)&At[cur][(wr * 64 + mf * 16 + (lane & 15)) * 32 + (lane >> 4) * 8];
#pragma unroll
        for (int nf = 0; nf < 4; nf++)
            bfr[nf] = *(const short8*)&Bt[cur][(wc * 64 + nf * 16 + (lane & 15)) * 32 + (lane >> 4) * 8];
        __builtin_amdgcn_s_setprio(1);
#pragma unroll
        for (int mf = 0; mf < 4; mf++)
#pragma unroll
            for (int nf = 0; nf < 4; nf++)
                acc[mf][nf] = __builtin_amdgcn_mfma_f32_16x16x32_bf16(af[mf], bfr[nf], acc[mf][nf], 0, 0, 0);
        __builtin_amdgcn_s_setprio(0);
        if (more) writeB(cur ^ 1);
        __syncthreads();
    }

#pragma unroll
    for (int nf = 0; nf < 4; nf++) {
        const int n = nbase + wc * 64 + nf * 16 + (lane & 15);
        const float bv = bias[n];
#pragma unroll
        for (int mf = 0; mf < 4; mf++) {
            const int m0 = mbase + wr * 64 + mf * 16 + (lane >> 4) * 4;
#pragma unroll
            for (int r = 0; r < 4; r++) {
                const int m = m0 + r;
                Cout[(long)m * Dm + n] = acc[mf][nf][r] + bv;
            }
        }
    }
}

// ---------------------------------------------------------------------------
// Fused QKV GEMM (R9/R11-proven): one 1536-block dispatch, t = blockIdx.y>>3
// selects {X, W slab, bias, scale, output} (block-uniform).
// A fp32 reg-staged with in-flight cvt; B bf16 via glds w=16.
// ---------------------------------------------------------------------------
__global__ __launch_bounds__(256) void gemm_qkv(
    const float* __restrict__ Xq, const float* __restrict__ Xk,
    const float* __restrict__ Xv, const u16* __restrict__ Wb3,
    const float* __restrict__ bq, const float* __restrict__ bk,
    const float* __restrict__ bv, u16* __restrict__ Out3)
{
    __shared__ u16 At[2][128 * 32];
    __shared__ u16 Bt[2][128 * 32];

    const int tid = threadIdx.x;
    const int lane = tid & 63, wid = tid >> 6;
    const int wr = wid >> 1, wc = wid & 1;
    const int mbase = blockIdx.x * 128;
    const int t = blockIdx.y >> 3;              // 0:Q 1:K 2:V (block-uniform)
    const int nbase = (blockIdx.y & 7) * 128;
    const float* X = t == 0 ? Xq : (t == 1 ? Xk : Xv);
    const u16* Bw = Wb3 + (size_t)t * Dm * Dm;
    const float* bias = t == 0 ? bq : (t == 1 ? bk : bv);
    const float scale = t == 0 ? QSCALE : 1.0f;
    u16* Cout = Out3 + (size_t)t * ((size_t)Bsz * Lseq * Dm);

    f32x4 acc[4][4];
#pragma unroll
    for (int i = 0; i < 4; i++)
#pragma unroll
        for (int j = 0; j < 4; j++) acc[i][j] = (f32x4)0.f;

    const int srow = lane >> 2;
    const int sseg = (lane & 3) * 8;
    auto stageB = [&](int kt, int buf) {
#pragma unroll
        for (int c = 0; c < 2; c++) {
            const int sec = wid * 2 + c;
            glds16(Bw + (long)(nbase + sec * 16 + srow) * Dm + (long)kt * 32 + sseg,
                   &Bt[buf][sec * 512]);
        }
    };

    u32x4 va[2];
    auto loadA = [&](int kt) {
#pragma unroll
        for (int i = 0; i < 2; i++) {
            int idx = i * 256 + tid;
            int row = idx >> 2, seg = idx & 3;
            va[i] = ld8_cvt(X + (long)(mbase + row) * Dm + (long)kt * 32 + seg * 8);
        }
    };
    auto writeA = [&](int buf) {
#pragma unroll
        for (int i = 0; i < 2; i++) {
            int idx = i * 256 + tid;
            *(u32x4*)&At[buf][idx * 8] = va[i];
        }
    };

    stageB(0, 0);
    loadA(0);
    writeA(0);
    __syncthreads();

    for (int kt = 0; kt < 32; kt++) {
        const int cur = kt & 1;
        const bool more = (kt + 1 < 32);
        if (more) {
            stageB(kt + 1, cur ^ 1);
            loadA(kt + 1);
        }
        short8 af[4], bfr[4];
#pragma unroll
        for (int mf = 0; mf < 4; mf++)
            af[mf] = *(const short8*)&At[cur][(wr * 64 + mf * 16 + (lane & 15)) * 32 + (lane >> 4) * 8];
#pragma unroll
        for (int nf = 0; nf < 4; nf++)
            bfr[nf] = *(const short8*)&Bt[cur][(wc * 64 + nf * 16 + (lane & 15)) * 32 + (lane >> 4) * 8];
        __builtin_amdgcn_s_setprio(1);
#pragma unroll
        for (int mf = 0; mf < 4; mf++)
#pragma unroll
            for (int nf = 0; nf < 4; nf++)
                acc[mf][nf] = __builtin_amdgcn_mfma_f32_16x16x32_bf16(af[mf], bfr[nf], acc[mf][nf], 0, 0, 0);
        __builtin_amdgcn_s_setprio(0);
        if (more) writeA(cur ^ 1);
        __syncthreads();
    }

#pragma unroll
    for (int nf = 0; nf < 4; nf++) {
        const int n = nbase + wc * 64 + nf * 16 + (lane & 15);
        const float bv = bias[n];
#pragma unroll
        for (int mf = 0; mf < 4; mf++) {
            const int m0 = mbase + wr * 64 + mf * 16 + (lane >> 4) * 4;
#pragma unroll
            for (int r = 0; r < 4; r++) {
                const int m = m0 + r;
                const float v = (acc[mf][nf][r] + bv) * scale;
                int b = m >> 11, l = m & 2047, h = n >> 6, dk = n & 63;
                long addr = ((long)(b * Hn + h) * Lseq + l) * Dk + dk;
                Cout[addr] = f2bf(v);
            }
        }
    }
}

// ---------------------------------------------------------------------------
// Flash attention (R12-proven structure; grid (B*H, L/128), qt reversed,
// 1024 blocks heavy-first — the scheduler backfills; DO NOT reduce block
// count, R13's 512-uniform-block variant regressed 107->158us).
// Single change vs R12: V transpose-staging via PAIR-WRITES —
// thread loads 2 adjacent kv rows x 8 d (2x dwordx4), writes 8x ds_write_b32
// packing (V[kv][d], V[kv+1][d]). XOR swizzle kvx = kv ^ swz(d) has granule 8
// so pairs stay adjacent + 4B aligned; write banks = 2-way (free).
// Read path unchanged. K: glds w=16 pre-swizzled. P [32q][64kv] ^ (q&7)<<3.
// Defer-max (THR=8) + lane-partial l. setprio around MFMA clusters.
// ---------------------------------------------------------------------------
__global__ __launch_bounds__(256) void attn_fwd(
    const u16* __restrict__ Qb, const u16* __restrict__ Kb,
    const u16* __restrict__ Vb, u16* __restrict__ Ctx)
{
    __shared__ u16 Kt[2][64 * 64];
    __shared__ u16 Vt[2][64 * 64];
    __shared__ u16 Pq[4][32 * 64];

    const int tid = threadIdx.x, lane = tid & 63, w = tid >> 6;
    const int qt = gridDim.y - 1 - blockIdx.y;  // heavy-first
    const int bh = blockIdx.x;
    const long base = (long)bh * Lseq * Dk;
    const int qw = qt * 128 + w * 32;

    const int krow_in_w = lane >> 3;
    const int kseg = lane & 7;
    // V staging coords: kv pair base 2*vp, d block vd0..vd0+7
    const int vp = tid >> 3;           // 0..31 -> kv rows 2vp, 2vp+1
    const int vd0 = (tid & 7) * 8;

    auto stage_k = [&](int kvbase, int buf) {
#pragma unroll
        for (int c = 0; c < 2; c++) {
            int kv = w * 16 + c * 8 + krow_in_w;
            int d0 = ((kseg ^ (kv & 7)) * 8);
            glds16(Kb + base + (long)(kvbase + kv) * Dk + d0,
                   &Kt[buf][(w * 16 + c * 8) * 64]);
        }
    };

    auto write_v = [&](int buf, const u32x4& r0, const u32x4& r1) {
        const u16* p0 = (const u16*)&r0;
        const u16* p1 = (const u16*)&r1;
#pragma unroll
        for (int j = 0; j < 8; j++) {
            int d = vd0 + j;
            u32 pr = (u32)p0[j] | ((u32)p1[j] << 16);
            int kvx = (2 * vp) ^ ((((d & 7) ^ (d >> 3)) & 7) << 3);
            *(u32*)&Vt[buf][d * 64 + kvx] = pr;
        }
    };

    // Q fragments in registers (log2 domain)
    short8 qfr[2][2];
#pragma unroll
    for (int qf = 0; qf < 2; qf++)
#pragma unroll
        for (int ks = 0; ks < 2; ks++) {
            int q = qw + qf * 16 + (lane & 15);
            int d0 = ks * 32 + (lane >> 4) * 8;
            qfr[qf][ks] = *(const short8*)(Qb + base + (long)q * Dk + d0);
        }

    f32x4 accT[4][2];  // ctx^T: [dkf][qf]
#pragma unroll
    for (int i = 0; i < 4; i++)
#pragma unroll
        for (int j = 0; j < 2; j++) accT[i][j] = (f32x4)0.f;
    float m_run[2] = {-__builtin_inff(), -__builtin_inff()};
    float l_part[2] = {0.f, 0.f};

    u32x4 vr0, vr1;
    stage_k(0, 0);
    vr0 = *(const u32x4*)(Vb + base + (long)(2 * vp) * Dk + vd0);
    vr1 = *(const u32x4*)(Vb + base + (long)(2 * vp + 1) * Dk + vd0);
    write_v(0, vr0, vr1);
    __syncthreads();

    const int nkv = qt * 2 + 2;
    const int myn = ((qw + 31) >> 6) + 1;  // tiles this wave computes

    for (int kvt = 0; kvt < nkv; kvt++) {
        const int cur = kvt & 1;
        const bool more = (kvt + 1 < nkv);
        const int kvbase = kvt * 64;

        if (more) {
            stage_k(kvbase + 64, cur ^ 1);
            vr0 = *(const u32x4*)(Vb + base + (long)(kvbase + 64 + 2 * vp) * Dk + vd0);
            vr1 = *(const u32x4*)(Vb + base + (long)(kvbase + 64 + 2 * vp + 1) * Dk + vd0);
        }

        if (kvt < myn) {
            // ---- S^T = K @ Q^T
            f32x4 st[4][2];
#pragma unroll
            for (int i = 0; i < 4; i++)
#pragma unroll
                for (int j = 0; j < 2; j++) st[i][j] = (f32x4)0.f;
            __builtin_amdgcn_s_setprio(1);
#pragma unroll
            for (int ks = 0; ks < 2; ks++) {
                short8 kf[4];
#pragma unroll
                for (int kvf = 0; kvf < 4; kvf++) {
                    int row = kvf * 16 + (lane & 15);
                    int d0 = ks * 32 + (lane >> 4) * 8;
                    kf[kvf] = *(const short8*)&Kt[cur][row * 64 + (d0 ^ ((row & 7) << 3))];
                }
#pragma unroll
                for (int kvf = 0; kvf < 4; kvf++)
#pragma unroll
                    for (int qf = 0; qf < 2; qf++)
                        st[kvf][qf] = __builtin_amdgcn_mfma_f32_16x16x32_bf16(kf[kvf], qfr[qf][ks], st[kvf][qf], 0, 0, 0);
            }
            __builtin_amdgcn_s_setprio(0);

            // ---- causal mask (diagonal tiles only)
            if ((kvbase + 63) > qw) {
#pragma unroll
                for (int qf = 0; qf < 2; qf++) {
                    const int q = qw + qf * 16 + (lane & 15);
#pragma unroll
                    for (int kvf = 0; kvf < 4; kvf++)
#pragma unroll
                        for (int r = 0; r < 4; r++) {
                            int kv = kvbase + kvf * 16 + (lane >> 4) * 4 + r;
                            if (kv > q) st[kvf][qf][r] = -1e30f;
                        }
                }
            }

            // ---- online softmax (base 2), defer-max, lane-partial l
#pragma unroll
            for (int qf = 0; qf < 2; qf++) {
                float tmax = st[0][qf][0];
#pragma unroll
                for (int kvf = 0; kvf < 4; kvf++)
#pragma unroll
                    for (int r = 0; r < 4; r++) tmax = fmaxf(tmax, st[kvf][qf][r]);
                tmax = fmaxf(tmax, __shfl_xor(tmax, 16, 64));
                tmax = fmaxf(tmax, __shfl_xor(tmax, 32, 64));
                const bool norescale = __all((int)(tmax <= m_run[qf] + 8.f));
                if (!norescale) {
                    const float mnew = fmaxf(m_run[qf], tmax);
                    const float sc = __builtin_exp2f(m_run[qf] - mnew);
                    m_run[qf] = mnew;
                    l_part[qf] *= sc;
#pragma unroll
                    for (int dkf = 0; dkf < 4; dkf++)
#pragma unroll
                        for (int r = 0; r < 4; r++) accT[dkf][qf][r] *= sc;
                }
                const float mq = m_run[qf];
                float ts = 0.f;
#pragma unroll
                for (int kvf = 0; kvf < 4; kvf++)
#pragma unroll
                    for (int r = 0; r < 4; r++) {
                        float p = __builtin_exp2f(st[kvf][qf][r] - mq);
                        st[kvf][qf][r] = p;
                        ts += p;
                    }
                l_part[qf] += ts;
                const int qrow = qf * 16 + (lane & 15);
#pragma unroll
                for (int kvf = 0; kvf < 4; kvf++) {
                    u32x2 pk;
                    pk[0] = pk2(st[kvf][qf][0], st[kvf][qf][1]);
                    pk[1] = pk2(st[kvf][qf][2], st[kvf][qf][3]);
                    int kvi = (kvf * 16 + (lane >> 4) * 4) ^ ((lane & 7) << 3);
                    *(u32x2*)&Pq[w][qrow * 64 + kvi] = pk;
                }
            }

            // ---- PV: ctx^T += V^T @ P^T
#pragma unroll
            for (int kf2 = 0; kf2 < 2; kf2++) {
                short8 vfr[4];
#pragma unroll
                for (int dkf = 0; dkf < 4; dkf++) {
                    int d = dkf * 16 + (lane & 15);
                    int kvi = (kf2 * 32 + (lane >> 4) * 8) ^ ((((d & 7) ^ (d >> 3)) & 7) << 3);
                    vfr[dkf] = *(const short8*)&Vt[cur][d * 64 + kvi];
                }
                short8 pfr[2];
#pragma unroll
                for (int qf = 0; qf < 2; qf++) {
                    int qrow = qf * 16 + (lane & 15);
                    int kvi = (kf2 * 32 + (lane >> 4) * 8) ^ ((lane & 7) << 3);
                    pfr[qf] = *(const short8*)&Pq[w][qrow * 64 + kvi];
                }
                __builtin_amdgcn_s_setprio(1);
#pragma unroll
                for (int dkf = 0; dkf < 4; dkf++)
#pragma unroll
                    for (int qf = 0; qf < 2; qf++)
                        accT[dkf][qf] = __builtin_amdgcn_mfma_f32_16x16x32_bf16(vfr[dkf], pfr[qf], accT[dkf][qf], 0, 0, 0);
                __builtin_amdgcn_s_setprio(0);
            }
        }

        // write staged V regs into the other buffer
        if (more) write_v(cur ^ 1, vr0, vr1);
        __syncthreads();  // drains glds (vmcnt) for buf^1
    }

    // ---- epilogue: reduce l, divide, write bf16 [B,L,D]
    const int b = bh >> 4, h = bh & 15;
#pragma unroll
    for (int qf = 0; qf < 2; qf++) {
        float l = l_part[qf];
        l += __shfl_xor(l, 16, 64);
        l += __shfl_xor(l, 32, 64);
        const float inv = 1.f / l;
        const int q = qw + qf * 16 + (lane & 15);
#pragma unroll
        for (int dkf = 0; dkf < 4; dkf++) {
            const int dk0 = dkf * 16 + (lane >> 4) * 4;
            u32x2 o;
            o[0] = pk2(accT[dkf][qf][0] * inv, accT[dkf][qf][1] * inv);
            o[1] = pk2(accT[dkf][qf][2] * inv, accT[dkf][qf][3] * inv);
            long addr = ((long)b * Lseq + q) * Dm + h * Dk + dk0;
            *(u32x2*)(Ctx + addr) = o;
        }
    }
}

// ---------------------------------------------------------------------------
extern "C" void kernel_launch(void* const* d_in, const int* in_sizes, int n_in,
                              void* d_out, int out_size, void* d_ws, size_t ws_size,
                              hipStream_t stream)
{
    const float* query = (const float*)d_in[0];
    const float* key_  = (const float*)d_in[1];
    const float* value = (const float*)d_in[2];
    const float* Wq = (const float*)d_in[3];
    const float* bq = (const float*)d_in[4];
    const float* Wk = (const float*)d_in[5];
    const float* bk = (const float*)d_in[6];
    const float* Wv = (const float*)d_in[7];
    const float* bv = (const float*)d_in[8];
    const float* Wo = (const float*)d_in[9];
    const float* bo = (const float*)d_in[10];
    // d_in[11] = attn_mask (bool causal) — derived from indices instead.

    float* out = (float*)d_out;
    const size_t tens = (size_t)Bsz * Lseq * Dm;   // 8,388,608
    const size_t wTot = (size_t)Dm * Dm;           // 1,048,576
    // ws layout (4*tens*2B = 67.1 MB, proven available):
    u16* Qb = (u16*)d_ws;        // bf16 [B,H,L,DK] (Q pre-scaled)
    u16* Kb = Qb + tens;
    u16* Vb = Kb + tens;
    u16* Cx = Vb + tens;         // attn output [B,L,D]
    u16* Wqb = Cx;               // Wq/Wk/Wv bf16 live in Cx slot until attn

    dim3 blk(256), g(64, 8), gq(64, 24);
    const int n8w = (int)(wTot / 8);
    const int gw = (n8w + 255) / 256;

    cvt_w3<<<dim3(gw, 3), blk, 0, stream>>>(Wq, Wk, Wv, Wqb, n8w);
    gemm_qkv<<<gq, blk, 0, stream>>>(query, key_, value, Wqb, bq, bk, bv, Qb);
    attn_fwd<<<dim3(Bsz * Hn, Lseq / 128), blk, 0, stream>>>(Qb, Kb, Vb, Cx);
    gemm_oproj<<<g, blk, 0, stream>>>(Cx, Wo, bo, out);
}

// Round 15
// 209.411 us; speedup vs baseline: 1.2592x; 1.0168x over previous
//
#include <hip/hip_runtime.h>
#include <hip/hip_bf16.h>
#include <stdint.h>

typedef unsigned short u16;
typedef unsigned int u32;
typedef short short8 __attribute__((ext_vector_type(8)));
typedef float f32x4 __attribute__((ext_vector_type(4)));
typedef float f32x16 __attribute__((ext_vector_type(16)));
typedef u32 u32x4 __attribute__((ext_vector_type(4)));
typedef u32 u32x2 __attribute__((ext_vector_type(2)));

#define DEV static __device__ __forceinline__

constexpr int Bsz = 4, Lseq = 2048, Dm = 1024, Hn = 16, Dk = 64;
constexpr float LOG2E = 1.44269504088896340736f;
constexpr float QSCALE = 0.125f * LOG2E;  // folded into Q projection

DEV u16 f2bf(float x) {
    u32 u = __builtin_bit_cast(u32, x);
    return (u16)((u + 0x7fffu + ((u >> 16) & 1u)) >> 16);
}

// pack 2 fp32 -> 2 bf16 in a u32 via HW v_cvt_pk_bf16_f32 path
DEV u32 pk2(float a, float b) {
    __hip_bfloat162 h = __float22bfloat162_rn(float2{a, b});
    u32 r;
    __builtin_memcpy(&r, &h, 4);
    return r;
}

// load 8 consecutive fp32, RNE to bf16, pack as u32x4
DEV u32x4 ld8_cvt(const float* p) {
    f32x4 lo = *(const f32x4*)p;
    f32x4 hi = *(const f32x4*)(p + 4);
    u32x4 r;
    r[0] = pk2(lo[0], lo[1]);
    r[1] = pk2(lo[2], lo[3]);
    r[2] = pk2(hi[0], hi[1]);
    r[3] = pk2(hi[2], hi[3]);
    return r;
}

// async global->LDS, 16B per lane; lds dest = wave-uniform base + lane*16
DEV void glds16(const void* g, void* l) {
    __builtin_amdgcn_global_load_lds(
        (const __attribute__((address_space(1))) void*)g,
        (__attribute__((address_space(3))) void*)l, 16, 0, 0);
}

// v_permlane32_swap_b32: vdst lanes 32..63 <-> vsrc lanes 0..31.
// After: a=[l<32: a_old[l] | l>=32: b_old[l-32]], b=[l<32: a_old[l+32] | l>=32: b_old[l]]
DEV void pswap(u32& a, u32& b) {
    asm volatile("v_permlane32_swap_b32 %0, %1" : "+v"(a), "+v"(b));
}

DEV short8 mk8(u32 w0, u32 w1, u32 w2, u32 w3) {
    u32x4 t;
    t[0] = w0; t[1] = w1; t[2] = w2; t[3] = w3;
    short8 r;
    __builtin_memcpy(&r, &t, 16);
    return r;
}

// ---------------------------------------------------------------------------
// fp32 -> bf16 conversion: 3 weight matrices in one dispatch.
// ---------------------------------------------------------------------------
__global__ __launch_bounds__(256) void cvt_w3(
    const float* __restrict__ a, const float* __restrict__ b,
    const float* __restrict__ c, u16* __restrict__ d, int n8)
{
    int i = blockIdx.x * 256 + threadIdx.x;
    if (i >= n8) return;
    const float* s = blockIdx.y == 0 ? a : (blockIdx.y == 1 ? b : c);
    ((u32x4*)(d + (size_t)blockIdx.y * (size_t)n8 * 8))[i] = ld8_cvt(s + (long)i * 8);
}

// ---------------------------------------------------------------------------
// Output projection (R12-proven): out[M,N] fp32 = Cx(bf16) @ Wo^T + bo.
// ---------------------------------------------------------------------------
__global__ __launch_bounds__(256) void gemm_oproj(
    const u16* __restrict__ A, const float* __restrict__ W,
    const float* __restrict__ bias, float* __restrict__ Cout)
{
    __shared__ u16 At[2][128 * 32];
    __shared__ u16 Bt[2][128 * 32];

    const int tid = threadIdx.x;
    const int lane = tid & 63, wid = tid >> 6;
    const int wr = wid >> 1, wc = wid & 1;
    const int mbase = blockIdx.x * 128, nbase = blockIdx.y * 128;

    f32x4 acc[4][4];
#pragma unroll
    for (int i = 0; i < 4; i++)
#pragma unroll
        for (int j = 0; j < 4; j++) acc[i][j] = (f32x4)0.f;

    const int srow = lane >> 2;
    const int sseg = (lane & 3) * 8;
    auto stageA = [&](int kt, int buf) {
#pragma unroll
        for (int c = 0; c < 2; c++) {
            const int sec = wid * 2 + c;
            glds16(A + (long)(mbase + sec * 16 + srow) * Dm + (long)kt * 32 + sseg,
                   &At[buf][sec * 512]);
        }
    };

    u32x4 vb[2];
    auto loadB = [&](int kt) {
#pragma unroll
        for (int i = 0; i < 2; i++) {
            int idx = i * 256 + tid;
            int row = idx >> 2, seg = idx & 3;
            vb[i] = ld8_cvt(W + (long)(nbase + row) * Dm + (long)kt * 32 + seg * 8);
        }
    };
    auto writeB = [&](int buf) {
#pragma unroll
        for (int i = 0; i < 2; i++) {
            int idx = i * 256 + tid;
            *(u32x4*)&Bt[buf][idx * 8] = vb[i];
        }
    };

    stageA(0, 0);
    loadB(0);
    writeB(0);
    __syncthreads();

    for (int kt = 0; kt < 32; kt++) {
        const int cur = kt & 1;
        const bool more = (kt + 1 < 32);
        if (more) {
            stageA(kt + 1, cur ^ 1);
            loadB(kt + 1);
        }
        short8 af[4], bfr[4];
#pragma unroll
        for (int mf = 0; mf < 4; mf++)
            af[mf] = *(const short8*)&At[cur][(wr * 64 + mf * 16 + (lane & 15)) * 32 + (lane >> 4) * 8];
#pragma unroll
        for (int nf = 0; nf < 4; nf++)
            bfr[nf] = *(const short8*)&Bt[cur][(wc * 64 + nf * 16 + (lane & 15)) * 32 + (lane >> 4) * 8];
        __builtin_amdgcn_s_setprio(1);
#pragma unroll
        for (int mf = 0; mf < 4; mf++)
#pragma unroll
            for (int nf = 0; nf < 4; nf++)
                acc[mf][nf] = __builtin_amdgcn_mfma_f32_16x16x32_bf16(af[mf], bfr[nf], acc[mf][nf], 0, 0, 0);
        __builtin_amdgcn_s_setprio(0);
        if (more) writeB(cur ^ 1);
        __syncthreads();
    }

#pragma unroll
    for (int nf = 0; nf < 4; nf++) {
        const int n = nbase + wc * 64 + nf * 16 + (lane & 15);
        const float bv = bias[n];
#pragma unroll
        for (int mf = 0; mf < 4; mf++) {
            const int m0 = mbase + wr * 64 + mf * 16 + (lane >> 4) * 4;
#pragma unroll
            for (int r = 0; r < 4; r++) {
                const int m = m0 + r;
                Cout[(long)m * Dm + n] = acc[mf][nf][r] + bv;
            }
        }
    }
}

// ---------------------------------------------------------------------------
// Fused QKV GEMM (R9/R11-proven): one 1536-block dispatch, t = blockIdx.y>>3
// selects {X, W slab, bias, scale, output} (block-uniform).
// ---------------------------------------------------------------------------
__global__ __launch_bounds__(256) void gemm_qkv(
    const float* __restrict__ Xq, const float* __restrict__ Xk,
    const float* __restrict__ Xv, const u16* __restrict__ Wb3,
    const float* __restrict__ bq, const float* __restrict__ bk,
    const float* __restrict__ bv, u16* __restrict__ Out3)
{
    __shared__ u16 At[2][128 * 32];
    __shared__ u16 Bt[2][128 * 32];

    const int tid = threadIdx.x;
    const int lane = tid & 63, wid = tid >> 6;
    const int wr = wid >> 1, wc = wid & 1;
    const int mbase = blockIdx.x * 128;
    const int t = blockIdx.y >> 3;              // 0:Q 1:K 2:V (block-uniform)
    const int nbase = (blockIdx.y & 7) * 128;
    const float* X = t == 0 ? Xq : (t == 1 ? Xk : Xv);
    const u16* Bw = Wb3 + (size_t)t * Dm * Dm;
    const float* bias = t == 0 ? bq : (t == 1 ? bk : bv);
    const float scale = t == 0 ? QSCALE : 1.0f;
    u16* Cout = Out3 + (size_t)t * ((size_t)Bsz * Lseq * Dm);

    f32x4 acc[4][4];
#pragma unroll
    for (int i = 0; i < 4; i++)
#pragma unroll
        for (int j = 0; j < 4; j++) acc[i][j] = (f32x4)0.f;

    const int srow = lane >> 2;
    const int sseg = (lane & 3) * 8;
    auto stageB = [&](int kt, int buf) {
#pragma unroll
        for (int c = 0; c < 2; c++) {
            const int sec = wid * 2 + c;
            glds16(Bw + (long)(nbase + sec * 16 + srow) * Dm + (long)kt * 32 + sseg,
                   &Bt[buf][sec * 512]);
        }
    };

    u32x4 va[2];
    auto loadA = [&](int kt) {
#pragma unroll
        for (int i = 0; i < 2; i++) {
            int idx = i * 256 + tid;
            int row = idx >> 2, seg = idx & 3;
            va[i] = ld8_cvt(X + (long)(mbase + row) * Dm + (long)kt * 32 + seg * 8);
        }
    };
    auto writeA = [&](int buf) {
#pragma unroll
        for (int i = 0; i < 2; i++) {
            int idx = i * 256 + tid;
            *(u32x4*)&At[buf][idx * 8] = va[i];
        }
    };

    stageB(0, 0);
    loadA(0);
    writeA(0);
    __syncthreads();

    for (int kt = 0; kt < 32; kt++) {
        const int cur = kt & 1;
        const bool more = (kt + 1 < 32);
        if (more) {
            stageB(kt + 1, cur ^ 1);
            loadA(kt + 1);
        }
        short8 af[4], bfr[4];
#pragma unroll
        for (int mf = 0; mf < 4; mf++)
            af[mf] = *(const short8*)&At[cur][(wr * 64 + mf * 16 + (lane & 15)) * 32 + (lane >> 4) * 8];
#pragma unroll
        for (int nf = 0; nf < 4; nf++)
            bfr[nf] = *(const short8*)&Bt[cur][(wc * 64 + nf * 16 + (lane & 15)) * 32 + (lane >> 4) * 8];
        __builtin_amdgcn_s_setprio(1);
#pragma unroll
        for (int mf = 0; mf < 4; mf++)
#pragma unroll
            for (int nf = 0; nf < 4; nf++)
                acc[mf][nf] = __builtin_amdgcn_mfma_f32_16x16x32_bf16(af[mf], bfr[nf], acc[mf][nf], 0, 0, 0);
        __builtin_amdgcn_s_setprio(0);
        if (more) writeA(cur ^ 1);
        __syncthreads();
    }

#pragma unroll
    for (int nf = 0; nf < 4; nf++) {
        const int n = nbase + wc * 64 + nf * 16 + (lane & 15);
        const float bv = bias[n];
#pragma unroll
        for (int mf = 0; mf < 4; mf++) {
            const int m0 = mbase + wr * 64 + mf * 16 + (lane >> 4) * 4;
#pragma unroll
            for (int r = 0; r < 4; r++) {
                const int m = m0 + r;
                const float v = (acc[mf][nf][r] + bv) * scale;
                int b = m >> 11, l = m & 2047, h = n >> 6, dk = n & 63;
                long addr = ((long)(b * Hn + h) * Lseq + l) * Dk + dk;
                Cout[addr] = f2bf(v);
            }
        }
    }
}

// ---------------------------------------------------------------------------
// Flash attention, 32x32 MFMA + in-register P (T12 permlane32_swap).
// Grid (B*H, L/128) qt-reversed, 1024 blocks (R13: don't reduce count).
// Block 256 = 4 waves; wave w owns q rows [qt*128+w*32, +32), ONE q per lane
// (q = qw + (lane&31); lane and lane^32 hold complementary kv/dk rows).
// S^T = mfma_32x32x16(K-frag, Q-frag): col=lane&31=q,
//   row=(reg&3)+8*(reg>>2)+4*(lane>>5). Softmax: 31 in-lane fmax + 1 shfl.
// P never touches LDS: B-operand frags built with cvt_pk + permlane32_swap
//   (rows j=0..3 of each 8-row B-group live in hi=0 lanes, j=4..7 in hi=1 —
//   exactly the vdst-upper<->vsrc-lower swap).
// K: glds w=16 pre-swizzled [64][64]; V: pair-write transpose Vt[d][kv^swz].
// LDS 32 KB (Pq deleted). Defer-max (THR=8) + lane-partial l.
// ---------------------------------------------------------------------------
__global__ __launch_bounds__(256) void attn_fwd(
    const u16* __restrict__ Qb, const u16* __restrict__ Kb,
    const u16* __restrict__ Vb, u16* __restrict__ Ctx)
{
    __shared__ u16 Kt[2][64 * 64];
    __shared__ u16 Vt[2][64 * 64];

    const int tid = threadIdx.x, lane = tid & 63, w = tid >> 6;
    const int qt = gridDim.y - 1 - blockIdx.y;  // heavy-first
    const int bh = blockIdx.x;
    const long base = (long)bh * Lseq * Dk;
    const int qw = qt * 128 + w * 32;
    const int qcol = lane & 31, hi = lane >> 5;

    const int krow_in_w = lane >> 3;
    const int kseg = lane & 7;
    const int vp = tid >> 3;           // kv pair base 2*vp
    const int vd0 = (tid & 7) * 8;

    auto stage_k = [&](int kvbase, int buf) {
#pragma unroll
        for (int c = 0; c < 2; c++) {
            int kv = w * 16 + c * 8 + krow_in_w;
            int d0 = ((kseg ^ (kv & 7)) * 8);
            glds16(Kb + base + (long)(kvbase + kv) * Dk + d0,
                   &Kt[buf][(w * 16 + c * 8) * 64]);
        }
    };

    auto write_v = [&](int buf, const u32x4& r0, const u32x4& r1) {
        const u16* p0 = (const u16*)&r0;
        const u16* p1 = (const u16*)&r1;
#pragma unroll
        for (int j = 0; j < 8; j++) {
            int d = vd0 + j;
            u32 pr = (u32)p0[j] | ((u32)p1[j] << 16);
            int kvx = (2 * vp) ^ ((((d & 7) ^ (d >> 3)) & 7) << 3);
            *(u32*)&Vt[buf][d * 64 + kvx] = pr;
        }
    };

    // Q fragments: B-operand, q = qw + qcol, k-slice ks: d = ks*16 + hi*8
    short8 qfr[4];
#pragma unroll
    for (int ks = 0; ks < 4; ks++)
        qfr[ks] = *(const short8*)(Qb + base + (long)(qw + qcol) * Dk + ks * 16 + hi * 8);

    f32x16 acc0 = (f32x16)0.f, acc1 = (f32x16)0.f;  // ctx^T dk-halves
    float m_run = -__builtin_inff();
    float l_part = 0.f;

    u32x4 vr0, vr1;
    stage_k(0, 0);
    vr0 = *(const u32x4*)(Vb + base + (long)(2 * vp) * Dk + vd0);
    vr1 = *(const u32x4*)(Vb + base + (long)(2 * vp + 1) * Dk + vd0);
    write_v(0, vr0, vr1);
    __syncthreads();

    const int nkv = qt * 2 + 2;
    const int myn = ((qw + 31) >> 6) + 1;  // tiles this wave computes

    for (int kvt = 0; kvt < nkv; kvt++) {
        const int cur = kvt & 1;
        const bool more = (kvt + 1 < nkv);
        const int kvbase = kvt * 64;

        if (more) {
            stage_k(kvbase + 64, cur ^ 1);
            vr0 = *(const u32x4*)(Vb + base + (long)(kvbase + 64 + 2 * vp) * Dk + vd0);
            vr1 = *(const u32x4*)(Vb + base + (long)(kvbase + 64 + 2 * vp + 1) * Dk + vd0);
        }

        if (kvt < myn) {
            // ---- S^T = K @ Q^T : two kv-halves of 32
            f32x16 st0 = (f32x16)0.f, st1 = (f32x16)0.f;
            __builtin_amdgcn_s_setprio(1);
#pragma unroll
            for (int ks = 0; ks < 4; ks++) {
                const int d0 = ks * 16 + hi * 8;
                {
                    const int kvrow = qcol;  // half 0
                    short8 kf = *(const short8*)&Kt[cur][kvrow * 64 + (d0 ^ ((kvrow & 7) << 3))];
                    st0 = __builtin_amdgcn_mfma_f32_32x32x16_bf16(kf, qfr[ks], st0, 0, 0, 0);
                }
                {
                    const int kvrow = 32 + qcol;  // half 1
                    short8 kf = *(const short8*)&Kt[cur][kvrow * 64 + (d0 ^ ((kvrow & 7) << 3))];
                    st1 = __builtin_amdgcn_mfma_f32_32x32x16_bf16(kf, qfr[ks], st1, 0, 0, 0);
                }
            }
            __builtin_amdgcn_s_setprio(0);

            // ---- causal mask (diagonal tiles only)
            if ((kvbase + 63) > qw) {
                const int q = qw + qcol;
#pragma unroll
                for (int r = 0; r < 16; r++) {
                    const int rr = (r & 3) + 8 * (r >> 2) + 4 * hi;
                    if (kvbase + rr > q) st0[r] = -1e30f;
                    if (kvbase + 32 + rr > q) st1[r] = -1e30f;
                }
            }

            // ---- online softmax (base 2), defer-max, lane-partial l
            float tmax = st0[0];
#pragma unroll
            for (int r = 1; r < 16; r++) tmax = fmaxf(tmax, st0[r]);
#pragma unroll
            for (int r = 0; r < 16; r++) tmax = fmaxf(tmax, st1[r]);
            tmax = fmaxf(tmax, __shfl_xor(tmax, 32, 64));
            const bool norescale = __all((int)(tmax <= m_run + 8.f));
            if (!norescale) {
                const float mnew = fmaxf(m_run, tmax);
                const float sc = __builtin_exp2f(m_run - mnew);
                m_run = mnew;
                l_part *= sc;
#pragma unroll
                for (int r = 0; r < 16; r++) {
                    acc0[r] *= sc;
                    acc1[r] *= sc;
                }
            }
            float ts = 0.f;
#pragma unroll
            for (int r = 0; r < 16; r++) {
                float p = __builtin_exp2f(st0[r] - m_run);
                st0[r] = p;
                ts += p;
            }
#pragma unroll
            for (int r = 0; r < 16; r++) {
                float p = __builtin_exp2f(st1[r] - m_run);
                st1[r] = p;
                ts += p;
            }
            l_part += ts;

            // ---- pack P -> 4 B-frags (kv slices of 16), zero LDS traffic
            short8 pf[4];
            {
                u32 a0 = pk2(st0[0], st0[1]), a1 = pk2(st0[2], st0[3]);
                u32 b0 = pk2(st0[4], st0[5]), b1 = pk2(st0[6], st0[7]);
                pswap(a0, b0);
                pswap(a1, b1);
                pf[0] = mk8(a0, a1, b0, b1);
                u32 c0 = pk2(st0[8], st0[9]), c1 = pk2(st0[10], st0[11]);
                u32 e0 = pk2(st0[12], st0[13]), e1 = pk2(st0[14], st0[15]);
                pswap(c0, e0);
                pswap(c1, e1);
                pf[1] = mk8(c0, c1, e0, e1);
            }
            {
                u32 a0 = pk2(st1[0], st1[1]), a1 = pk2(st1[2], st1[3]);
                u32 b0 = pk2(st1[4], st1[5]), b1 = pk2(st1[6], st1[7]);
                pswap(a0, b0);
                pswap(a1, b1);
                pf[2] = mk8(a0, a1, b0, b1);
                u32 c0 = pk2(st1[8], st1[9]), c1 = pk2(st1[10], st1[11]);
                u32 e0 = pk2(st1[12], st1[13]), e1 = pk2(st1[14], st1[15]);
                pswap(c0, e0);
                pswap(c1, e1);
                pf[3] = mk8(c0, c1, e0, e1);
            }

            // ---- PV: ctx^T += V^T @ P^T
            __builtin_amdgcn_s_setprio(1);
#pragma unroll
            for (int s = 0; s < 4; s++) {
                {
                    const int d = qcol;  // dk half 0
                    const int kvi = (s * 16 + hi * 8) ^ ((((d & 7) ^ (d >> 3)) & 7) << 3);
                    short8 vf = *(const short8*)&Vt[cur][d * 64 + kvi];
                    acc0 = __builtin_amdgcn_mfma_f32_32x32x16_bf16(vf, pf[s], acc0, 0, 0, 0);
                }
                {
                    const int d = 32 + qcol;  // dk half 1
                    const int kvi = (s * 16 + hi * 8) ^ ((((d & 7) ^ (d >> 3)) & 7) << 3);
                    short8 vf = *(const short8*)&Vt[cur][d * 64 + kvi];
                    acc1 = __builtin_amdgcn_mfma_f32_32x32x16_bf16(vf, pf[s], acc1, 0, 0, 0);
                }
            }
            __builtin_amdgcn_s_setprio(0);
        }

        if (more) write_v(cur ^ 1, vr0, vr1);
        __syncthreads();  // drains glds (vmcnt) for buf^1
    }

    // ---- epilogue: reduce l across kv-split lanes, divide, write bf16
    const int b = bh >> 4, hh = bh & 15;
    float l = l_part + __shfl_xor(l_part, 32, 64);
    const float inv = 1.f / l;
    const int q = qw + qcol;
    const long rowaddr = ((long)b * Lseq + q) * Dm + hh * Dk;
#pragma unroll
    for (int quad = 0; quad < 4; quad++) {
        {
            const int dk0 = quad * 8 + 4 * hi;  // acc row = (r&3)+8*quad+4*hi
            u32x2 o;
            o[0] = pk2(acc0[quad * 4 + 0] * inv, acc0[quad * 4 + 1] * inv);
            o[1] = pk2(acc0[quad * 4 + 2] * inv, acc0[quad * 4 + 3] * inv);
            *(u32x2*)(Ctx + rowaddr + dk0) = o;
        }
        {
            const int dk0 = 32 + quad * 8 + 4 * hi;
            u32x2 o;
            o[0] = pk2(acc1[quad * 4 + 0] * inv, acc1[quad * 4 + 1] * inv);
            o[1] = pk2(acc1[quad * 4 + 2] * inv, acc1[quad * 4 + 3] * inv);
            *(u32x2*)(Ctx + rowaddr + dk0) = o;
        }
    }
}

// ---------------------------------------------------------------------------
extern "C" void kernel_launch(void* const* d_in, const int* in_sizes, int n_in,
                              void* d_out, int out_size, void* d_ws, size_t ws_size,
                              hipStream_t stream)
{
    const float* query = (const float*)d_in[0];
    const float* key_  = (const float*)d_in[1];
    const float* value = (const float*)d_in[2];
    const float* Wq = (const float*)d_in[3];
    const float* bq = (const float*)d_in[4];
    const float* Wk = (const float*)d_in[5];
    const float* bk = (const float*)d_in[6];
    const float* Wv = (const float*)d_in[7];
    const float* bv = (const float*)d_in[8];
    const float* Wo = (const float*)d_in[9];
    const float* bo = (const float*)d_in[10];
    // d_in[11] = attn_mask (bool causal) — derived from indices instead.

    float* out = (float*)d_out;
    const size_t tens = (size_t)Bsz * Lseq * Dm;   // 8,388,608
    const size_t wTot = (size_t)Dm * Dm;           // 1,048,576
    // ws layout (4*tens*2B = 67.1 MB, proven available):
    u16* Qb = (u16*)d_ws;        // bf16 [B,H,L,DK] (Q pre-scaled)
    u16* Kb = Qb + tens;
    u16* Vb = Kb + tens;
    u16* Cx = Vb + tens;         // attn output [B,L,D]
    u16* Wqb = Cx;               // Wq/Wk/Wv bf16 live in Cx slot until attn

    dim3 blk(256), g(64, 8), gq(64, 24);
    const int n8w = (int)(wTot / 8);
    const int gw = (n8w + 255) / 256;

    cvt_w3<<<dim3(gw, 3), blk, 0, stream>>>(Wq, Wk, Wv, Wqb, n8w);
    gemm_qkv<<<gq, blk, 0, stream>>>(query, key_, value, Wqb, bq, bk, bv, Qb);
    attn_fwd<<<dim3(Bsz * Hn, Lseq / 128), blk, 0, stream>>>(Qb, Kb, Vb, Cx);
    gemm_oproj<<<g, blk, 0, stream>>>(Cx, Wo, bo, out);
}